// Round 2
// baseline (316.453 us; speedup 1.0000x reference)
//
#include <hip/hip_runtime.h>

// out[b,c,h,w] = block_switch[h/8, w/8] ? -1.0f : image[b,c,h,w]
// image: [64, 3, 512, 512] fp32 ; block_switch: [64, 64] (bool -> int32 per harness)
//
// One float4 per lane per unroll step. A float4 starts at w = 4*k; 4k..4k+3
// share the same w/8 block (4k % 8 is 0 or 4) -> one mask lookup per float4.
//
// v3 changes vs v2 (total 315.5 us, kernel ~71 us of it):
//  - UNROLL 4 -> 8: per-CU outstanding read lines 128 -> 256, covering the
//    ~900-cycle HBM latency with margin (need ~145 lines in flight at
//    6.3 TB/s). v2's 128 was marginal -> read stream latency-exposed.
//  - bounds checks removed from the hot kernel: n4 (12,582,912) divides
//    exactly by TPB*UNROLL (2048); grid = 6144 exact. A tail kernel covers
//    any remainder (none for this problem shape).
//  - nontemporal load/store on streaming image/out kept; mask stays cached.
//  - conditional image load KEPT: skipping fully-masked 64B sectors saves
//    ~25% of read traffic (P(both 8-blocks in a sector masked) = 0.25).

typedef float f32x4 __attribute__((ext_vector_type(4)));

#define W 512
#define H 512
#define MASK_W 64      // W / 8
#define TPB 256
#define UNROLL 8

__global__ __launch_bounds__(TPB) void grid_crop_kernel(
    const f32x4* __restrict__ img,
    const int* __restrict__ mask,
    f32x4* __restrict__ out)
{
    int base = blockIdx.x * (TPB * UNROLL) + threadIdx.x;

    // Phase 1: issue all 8 mask loads (independent, L1-resident after warmup).
    int m[UNROLL];
#pragma unroll
    for (int u = 0; u < UNROLL; ++u) {
        int idx  = base + u * TPB;
        int elem = idx << 2;                 // flat float index
        int w    = elem & (W - 1);           // 0..511
        int h    = (elem >> 9) & (H - 1);    // 0..511  (W == 512 == 2^9)
        m[u] = mask[(h >> 3) * MASK_W + (w >> 3)];
    }

    // Phase 2: 8 independent exec-masked image loads -> all in flight at once.
    f32x4 v[UNROLL];
#pragma unroll
    for (int u = 0; u < UNROLL; ++u) {
        int idx = base + u * TPB;
        if (m[u] == 0) {
            v[u] = __builtin_nontemporal_load(&img[idx]);
        } else {
            v[u] = (f32x4){-1.0f, -1.0f, -1.0f, -1.0f};
        }
    }

    // Phase 3: dense streaming stores.
#pragma unroll
    for (int u = 0; u < UNROLL; ++u) {
        int idx = base + u * TPB;
        __builtin_nontemporal_store(v[u], &out[idx]);
    }
}

// Tail kernel for any remainder elements (not used for this problem's exact
// shape, but keeps kernel_launch correct for any out_size).
__global__ __launch_bounds__(TPB) void grid_crop_tail(
    const f32x4* __restrict__ img,
    const int* __restrict__ mask,
    f32x4* __restrict__ out,
    int start, int n4)
{
    int idx = start + blockIdx.x * blockDim.x + threadIdx.x;
    if (idx >= n4) return;
    int elem = idx << 2;
    int w = elem & (W - 1);
    int h = (elem >> 9) & (H - 1);
    int m = mask[(h >> 3) * MASK_W + (w >> 3)];
    f32x4 v;
    if (m == 0) {
        v = __builtin_nontemporal_load(&img[idx]);
    } else {
        v = (f32x4){-1.0f, -1.0f, -1.0f, -1.0f};
    }
    __builtin_nontemporal_store(v, &out[idx]);
}

extern "C" void kernel_launch(void* const* d_in, const int* in_sizes, int n_in,
                              void* d_out, int out_size, void* d_ws, size_t ws_size,
                              hipStream_t stream) {
    const f32x4* img  = (const f32x4*)d_in[0];
    const int*   mask = (const int*)d_in[1];
    f32x4*       out  = (f32x4*)d_out;

    int n4 = out_size >> 2;              // 64*3*512*512 / 4 = 12,582,912 float4
    int per_block = TPB * UNROLL;        // 2048 float4 per block
    int grid = n4 / per_block;           // 6144 blocks (exact for this shape)

    if (grid > 0) {
        grid_crop_kernel<<<grid, TPB, 0, stream>>>(img, mask, out);
    }

    int done = grid * per_block;
    int rem  = n4 - done;
    if (rem > 0) {
        int tgrid = (rem + TPB - 1) / TPB;
        grid_crop_tail<<<tgrid, TPB, 0, stream>>>(img, mask, out, done, n4);
    }
}